// Round 1
// baseline (4036.970 us; speedup 1.0000x reference)
//
#include <hip/hip_runtime.h>
#include <hip/hip_fp16.h>
#include <cstdint>
#include <cstddef>

// Problem constants (T, B, V, HID, L) from the reference.
#define TT 1024
#define BB 64
#define VV 256
#define HH 512
static const size_t TBH = (size_t)TT * BB * HH;   // 33,554,432 floats

#define AGENT __HIP_MEMORY_SCOPE_AGENT

typedef _Float16 half2v __attribute__((ext_vector_type(2)));
union U32H2 { unsigned u; half2v h; };

__device__ __forceinline__ unsigned pack_f16x2(float a, float b) {
    __half ha = __float2half_rn(a);
    __half hb = __float2half_rn(b);
    return (unsigned)__half_as_ushort(ha) | ((unsigned)__half_as_ushort(hb) << 16);
}

__device__ __forceinline__ float tanh_fast(float x) {
    // tanh(x) = sign(x) * (1 - e^-2|x|) / (1 + e^-2|x|)
    float ax = fabsf(x);
    float e = __expf(-2.0f * ax);
    float r = (1.0f - e) * __builtin_amdgcn_rcpf(1.0f + e);
    return copysignf(r, x);
}

__device__ __forceinline__ float fdot2(unsigned w, unsigned h, float acc) {
    U32H2 uw; uw.u = w;
    U32H2 uh; uh.u = h;
#if __has_builtin(__builtin_amdgcn_fdot2)
    return __builtin_amdgcn_fdot2(uw.h, uh.h, acc, false);
#else
    return acc + (float)uw.h[0] * (float)uh.h[0] + (float)uw.h[1] * (float)uh.h[1];
#endif
}

// ---------------------------------------------------------------------------
// Weight prep:
//  Wq0/Wq1 : recurrent Wh rows as f16x2 k-pairs   [512 rows][256 pairs]
//  Wp0/Wp1 : input-proj Wx^T as f16x2 k-pairs     [K/2 pairs][512 cols]
// ---------------------------------------------------------------------------
__global__ void pack_weights(const float* __restrict__ Wnet,
                             const float* __restrict__ Wdeep,
                             unsigned* __restrict__ Wq0, unsigned* __restrict__ Wq1,
                             unsigned* __restrict__ Wp0, unsigned* __restrict__ Wp1) {
    int id = blockIdx.x * 256 + threadIdx.x;
    const int NQ  = HH * (HH / 2);     // 131072
    const int NP0 = (VV / 2) * HH;     // 65536
    const int NP1 = (HH / 2) * HH;     // 131072
    if (id < NQ) {
        int i = id >> 8, jp = id & 255;
        const float* row = Wnet + (size_t)i * (VV + HH) + VV;   // Wh0[i][:]
        Wq0[id] = pack_f16x2(row[2 * jp], row[2 * jp + 1]);
        return;
    }
    id -= NQ;
    if (id < NQ) {
        int i = id >> 8, jp = id & 255;
        const float* row = Wdeep + (size_t)i * (2 * HH) + HH;   // Wh1[i][:]
        Wq1[id] = pack_f16x2(row[2 * jp], row[2 * jp + 1]);
        return;
    }
    id -= NQ;
    if (id < NP0) {
        int k2 = id >> 9, n = id & 511;                          // Wx0[n][2k2..]
        const float* row = Wnet + (size_t)n * (VV + HH);
        Wp0[id] = pack_f16x2(row[2 * k2], row[2 * k2 + 1]);
        return;
    }
    id -= NP0;
    if (id < NP1) {
        int k2 = id >> 9, n = id & 511;                          // Wx1[n][2k2..]
        const float* row = Wdeep + (size_t)n * (2 * HH);
        Wp1[id] = pack_f16x2(row[2 * k2], row[2 * k2 + 1]);
        return;
    }
}

// ---------------------------------------------------------------------------
// Input-projection GEMM (f16 dot2): C[M,512] = A[M,K] @ Wx^T + bias.
// A tile converted to f16x2 pairs in LDS (staged fully before any C write ->
// in-place safe for A == C).  Block: 1024 thr; thread t: 2 rows, 8 cols.
// ---------------------------------------------------------------------------
__device__ __forceinline__ void dot8(float* acc, unsigned a, uint4 w0, uint4 w1) {
    acc[0] = fdot2(w0.x, a, acc[0]);
    acc[1] = fdot2(w0.y, a, acc[1]);
    acc[2] = fdot2(w0.z, a, acc[2]);
    acc[3] = fdot2(w0.w, a, acc[3]);
    acc[4] = fdot2(w1.x, a, acc[4]);
    acc[5] = fdot2(w1.y, a, acc[5]);
    acc[6] = fdot2(w1.z, a, acc[6]);
    acc[7] = fdot2(w1.w, a, acc[7]);
}

__launch_bounds__(1024)
__global__ void xproj_f16(const float* __restrict__ A,
                          const unsigned* __restrict__ Wp,   // [K/2][512] f16x2
                          const float* __restrict__ bias,
                          float* __restrict__ C, int K) {
    extern __shared__ unsigned As2[];      // 32 rows * K/2 pairs
    const int m0 = blockIdx.x * 32;
    const int t = threadIdx.x;
    const int K2 = K >> 1;

    // stage + convert A tile (coalesced float4 reads)
    const int nf4 = 8 * K;                 // 32*K/4
    const float4* Ag = (const float4*)(A + (size_t)m0 * K);
    for (int idx = t; idx < nf4; idx += 1024) {
        float4 v = Ag[idx];
        As2[idx * 2]     = pack_f16x2(v.x, v.y);
        As2[idx * 2 + 1] = pack_f16x2(v.z, v.w);
    }
    __syncthreads();

    const int rg = t >> 6;                 // 2 rows per thread
    const int n0 = (t & 63) * 8;

    float acc0[8] = {0, 0, 0, 0, 0, 0, 0, 0};
    float acc1[8] = {0, 0, 0, 0, 0, 0, 0, 0};

    const unsigned* a0p = As2 + (size_t)(rg * 2) * K2;
    const unsigned* a1p = a0p + K2;

#pragma unroll 4
    for (int k2 = 0; k2 < K2; k2 += 2) {
        unsigned a00 = a0p[k2], a01 = a0p[k2 + 1];
        unsigned a10 = a1p[k2], a11 = a1p[k2 + 1];
        const uint4 w00 = *(const uint4*)(Wp + (size_t)k2 * 512 + n0);
        const uint4 w01 = *(const uint4*)(Wp + (size_t)k2 * 512 + n0 + 4);
        const uint4 w10 = *(const uint4*)(Wp + (size_t)(k2 + 1) * 512 + n0);
        const uint4 w11 = *(const uint4*)(Wp + (size_t)(k2 + 1) * 512 + n0 + 4);
        dot8(acc0, a00, w00, w01);
        dot8(acc1, a10, w00, w01);
        dot8(acc0, a01, w10, w11);
        dot8(acc1, a11, w10, w11);
    }

    float bv[8];
#pragma unroll
    for (int c = 0; c < 8; ++c) bv[c] = bias[n0 + c];

    float* Crow0 = C + (size_t)(m0 + rg * 2) * 512 + n0;
    float* Crow1 = Crow0 + 512;
    *(float4*)(Crow0)     = make_float4(acc0[0] + bv[0], acc0[1] + bv[1], acc0[2] + bv[2], acc0[3] + bv[3]);
    *(float4*)(Crow0 + 4) = make_float4(acc0[4] + bv[4], acc0[5] + bv[5], acc0[6] + bv[6], acc0[7] + bv[7]);
    *(float4*)(Crow1)     = make_float4(acc1[0] + bv[0], acc1[1] + bv[1], acc1[2] + bv[2], acc1[3] + bv[3]);
    *(float4*)(Crow1 + 4) = make_float4(acc1[4] + bv[4], acc1[5] + bv[5], acc1[6] + bv[6], acc1[7] + bv[7]);
}

// ---------------------------------------------------------------------------
// RNN scan, 2 CUs per batch element (K-split), register-resident weights.
// Grid: 128 WGs of 512 thr.  b = w&63, s = w>>6  -> pair (b, b+64) lands on
// the SAME XCD under round-robin blockIdx%8 dispatch (64%8==0), so the
// exchange stays in that XCD's L2.  Thread i owns row r=i over K-half s
// (128 f16x2 pairs = 128 VGPRs, loaded once and PINNED via opaque asm --
// previous build showed VGPR_Count=76 < 128: the compiler sank the weight
// loads into the t-loop, re-fetching 512B/thread/step from L2 (~2.2 kcyc/step
// of per-XCD L2 BW, the dominant stall).  Exchange: 64-bit fused
// {tag,payload} relaxed agent atomics, double-buffered by step parity;
// owner threads poll for exact tag.  One __syncthreads per step; h is
// shared through LDS as packed f16 (single rounding at the owner).
// ---------------------------------------------------------------------------
__launch_bounds__(512, 1)
__global__ void rnn_scan3(const unsigned* __restrict__ Wq,   // [512][256] f16x2
                          const float* __restrict__ h0,      // [B][512]
                          float* __restrict__ states,        // [T][B][512] in:pre out:h
                          float* __restrict__ last,          // [B][512]
                          unsigned long long* __restrict__ X) { // [B][2 owner][2 par][256]
    __shared__ unsigned short hsh16[2][256];   // h as f16, per step parity

    const int w = blockIdx.x;
    const int b = w & 63;
    const int s = w >> 6;
    const int r = threadIdx.x;          // my row, 0..511
    const int lane = r & 63;
    const int owner = r >> 8;           // WG (s==owner) finalizes row r
    const bool is_owner = (owner == s); // wave-uniform

    // --- weights for row r over K-half s: 32 uint4 in VGPRs ---
    uint4 wreg[32];
    {
        const uint4* Wr = (const uint4*)(Wq + (size_t)r * 256 + s * 128);
#pragma unroll
        for (int q = 0; q < 32; ++q) wreg[q] = Wr[q];
    }
    // Pin all 128 weight dwords in VGPRs.  The opaque volatile asm makes the
    // values non-rematerializable: the allocator can no longer sink the
    // global loads back into the 1024-iteration t-loop.  (128 pinned + ~50
    // live temps < 256 VGPR cap for 2 waves/SIMD -> no spill expected.)
#pragma unroll
    for (int q = 0; q < 32; ++q)
        asm volatile("" : "+v"(wreg[q].x), "+v"(wreg[q].y),
                          "+v"(wreg[q].z), "+v"(wreg[q].w));

    // --- hp: my K-half of h as f16x2 pairs, replicated per wave ---
    unsigned hp[2];
    {
        const float2* h2 = (const float2*)(h0 + (size_t)b * HH);
#pragma unroll
        for (int rr = 0; rr < 2; ++rr) {
            float2 v = h2[s * 128 + rr * 64 + lane];
            hp[rr] = pack_f16x2(v.x, v.y);
        }
    }

    // exchange slots (same address computed by writer and reader)
    unsigned long long* slotA = X + ((((size_t)b * 2 + owner) * 2 + 0) << 8) + (r & 255);
    unsigned long long* slotB = slotA + 256;

    size_t base = (size_t)b * HH;       // rowbase for t=0
    const size_t tstride = (size_t)BB * HH;

    float pre_cur = 0.f;
    if (is_owner) pre_cur = states[base + r];

    float h = 0.f;
    for (int t = 0; t < TT; ++t) {
        float pre_nxt = 0.f;
        if (is_owner && t + 1 < TT) pre_nxt = states[base + tstride + r];

        // partial for row r over K-half s: 128 dot2
        float a0 = 0.f, a1 = 0.f, a2 = 0.f, a3 = 0.f;
#pragma unroll
        for (int q = 0; q < 32; ++q) {
            const uint4 wv = wreg[q];
            const int j = q * 4;
            unsigned s0 = (unsigned)__builtin_amdgcn_readlane((int)hp[(j + 0) >> 6], (j + 0) & 63);
            unsigned s1 = (unsigned)__builtin_amdgcn_readlane((int)hp[(j + 1) >> 6], (j + 1) & 63);
            unsigned s2 = (unsigned)__builtin_amdgcn_readlane((int)hp[(j + 2) >> 6], (j + 2) & 63);
            unsigned s3 = (unsigned)__builtin_amdgcn_readlane((int)hp[(j + 3) >> 6], (j + 3) & 63);
            a0 = fdot2(wv.x, s0, a0);
            a1 = fdot2(wv.y, s1, a1);
            a2 = fdot2(wv.z, s2, a2);
            a3 = fdot2(wv.w, s3, a3);
        }
        float part = (a0 + a1) + (a2 + a3);

        const int p = t & 1;
        unsigned long long* slot = p ? slotB : slotA;
        if (!is_owner) {
            unsigned long long msg = ((unsigned long long)(unsigned)(t + 1) << 32)
                                   | (unsigned long long)__float_as_uint(part);
            __hip_atomic_store(slot, msg, __ATOMIC_RELAXED, AGENT);
        } else {
            unsigned long long v;
            do {
                v = __hip_atomic_load(slot, __ATOMIC_RELAXED, AGENT);
            } while ((unsigned)(v >> 32) != (unsigned)(t + 1));
            float pother = __uint_as_float((unsigned)v);
            h = tanh_fast(pre_cur + part + pother);
            states[base + r] = h;
            hsh16[p][r & 255] = __half_as_ushort(__float2half_rn(h));
        }
        __syncthreads();

        // repack: one dword = two adjacent rows' f16 values = one k-pair
        const unsigned* hh = (const unsigned*)hsh16[p];
#pragma unroll
        for (int rr = 0; rr < 2; ++rr) hp[rr] = hh[rr * 64 + lane];

        pre_cur = pre_nxt;
        base += tstride;
    }

    if (is_owner) last[(size_t)b * HH + r] = h;
}

// ---------------------------------------------------------------------------
extern "C" void kernel_launch(void* const* d_in, const int* in_sizes, int n_in,
                              void* d_out, int out_size, void* d_ws, size_t ws_size,
                              hipStream_t stream) {
    (void)in_sizes; (void)n_in; (void)out_size; (void)ws_size;
    const float* inputs = (const float*)d_in[0];   // (T,B,V)
    const float* H      = (const float*)d_in[1];   // (L,B,HID)
    const float* Wnet   = (const float*)d_in[2];   // (HID, V+HID)
    const float* bnet   = (const float*)d_in[3];   // (HID,)
    const float* Wdeep  = (const float*)d_in[4];   // (HID, 2*HID)
    const float* bdeep  = (const float*)d_in[5];   // (HID,)
    float* out = (float*)d_out;

    // workspace layout (X first for 8B alignment); ~2.3 MB total
    unsigned long long* X = (unsigned long long*)d_ws;  // 64*2*2*256 u64 = 512 KB
    unsigned* Wq0 = (unsigned*)(X + 64 * 2 * 2 * 256);  // 131072 u32
    unsigned* Wq1 = Wq0 + HH * (HH / 2);                // 131072 u32
    unsigned* Wp0 = Wq1 + HH * (HH / 2);                // 65536 u32
    unsigned* Wp1 = Wp0 + (VV / 2) * HH;                // 131072 u32

    // 1) pack weights (458752 ids / 256 = 1792 blocks)
    hipLaunchKernelGGL(pack_weights, dim3(1792), dim3(256), 0, stream,
                       Wnet, Wdeep, Wq0, Wq1, Wp0, Wp1);

    // 2) pre0 = inputs @ Wx0^T + b_net  -> d_out[0:TBH]
    hipLaunchKernelGGL(xproj_f16, dim3((TT * BB) / 32), dim3(1024),
                       32 * (VV / 2) * sizeof(unsigned), stream,
                       inputs, Wp0, bnet, out, VV);

    // 3) layer-0 scan
    hipLaunchKernelGGL(rnn_scan3, dim3(128), dim3(512), 0, stream,
                       Wq0, H, out, out + TBH, X);

    // 4) pre1 = states0 @ Wx1^T + b_deep (in-place over d_out)
    hipLaunchKernelGGL(xproj_f16, dim3((TT * BB) / 32), dim3(1024),
                       32 * (HH / 2) * sizeof(unsigned), stream,
                       out, Wp1, bdeep, out, HH);

    // 5) layer-1 scan (X reusable: exact-tag matching ignores stale tags)
    hipLaunchKernelGGL(rnn_scan3, dim3(128), dim3(512), 0, stream,
                       Wq1, H + (size_t)BB * HH, out, out + TBH + (size_t)BB * HH, X);
}